// Round 4
// baseline (156.620 us; speedup 1.0000x reference)
//
#include <hip/hip_runtime.h>
#include <hip/hip_cooperative_groups.h>
#include <math.h>

namespace cg = cooperative_groups;

#define NB 256
#define ND 768
#define MARGIN_F 0.2f
#define NKC 16            // k-chunks per matrix
#define KCF 48            // floats per k-chunk (12 float4)
#define PITCH 64          // LDS row pitch in floats (padded from 48)
#define NBLK 512          // 2 matrices * 16 tiles * 16 k-chunks

// One cooperative kernel, three phases separated by grid.sync():
//   Phase 1: d^2 partial planes [2][16][256][256] via 64x64 tiles, 4x4 register tiling
//   Phase 2: per (i, j-half): rebuild distance rows (sum 16 planes + sqrt), triplet sum
//   Phase 3: block 0 reduces 512 partials in fixed order (deterministic)
__global__ __launch_bounds__(256)
void fused_kernel(const float* __restrict__ Ximg,
                  const float* __restrict__ Xehr,
                  float* __restrict__ ws,
                  float* __restrict__ out) {
    cg::grid_group grid = cg::this_grid();

    __shared__ float lds[2 * 64 * PITCH];   // 32 KB, reused across phases
    __shared__ float wred[8];

    const int tid = threadIdx.x;
    const int bid = blockIdx.x;

    float* planes   = ws;                         // 2*16*256*256 floats = 8 MB
    float* partials = ws + 2 * NKC * NB * NB;     // 512 floats

    // ---------------- Phase 1: squared-distance partials ----------------
    {
        float* As = lds;
        float* Bs = lds + 64 * PITCH;

        const int m    = bid >> 8;        // 0 = img, 1 = ehr
        const int r    = bid & 255;
        const int tile = r >> 4;          // 0..15 (4x4 grid of 64x64 tiles)
        const int kc   = r & 15;          // k-chunk
        const int ti   = tile >> 2;
        const int tj   = tile & 3;
        const float* __restrict__ X = m ? Xehr : Ximg;

        const int base_col = kc * KCF;
        // stage 64 rows x 12 float4 per side (768 float4 = 3 x 256 threads),
        // XOR-swizzled within padded pitch
#pragma unroll
        for (int p = 0; p < 3; ++p) {
            const int idx = tid + (p << 8);          // 0..767
            const int row = idx / 12;                // 0..63
            const int c4  = idx - row * 12;          // 0..11
            const int sw  = (row >> 2) & 7;
            const float4 va = *(const float4*)(&X[(size_t)(ti * 64 + row) * ND + base_col + c4 * 4]);
            *(float4*)(&As[row * PITCH + ((c4 ^ sw) << 2)]) = va;
            const float4 vb = *(const float4*)(&X[(size_t)(tj * 64 + row) * ND + base_col + c4 * 4]);
            *(float4*)(&Bs[row * PITCH + ((c4 ^ sw) << 2)]) = vb;
        }
        __syncthreads();

        const int li = tid >> 4;          // 0..15 -> rows 4li..4li+3
        const int lj = tid & 15;          // 0..15 -> cols 4lj..4lj+3
        const int swa = li & 7;
        const int swb = lj & 7;

        float acc[4][4];
#pragma unroll
        for (int a = 0; a < 4; ++a)
#pragma unroll
            for (int b = 0; b < 4; ++b) acc[a][b] = 0.0f;

#pragma unroll 4
        for (int q = 0; q < 12; ++q) {
            float4 av[4], bv[4];
#pragma unroll
            for (int a = 0; a < 4; ++a)
                av[a] = *(const float4*)(&As[(4 * li + a) * PITCH + ((q ^ swa) << 2)]);
#pragma unroll
            for (int b = 0; b < 4; ++b)
                bv[b] = *(const float4*)(&Bs[(4 * lj + b) * PITCH + ((q ^ swb) << 2)]);
#pragma unroll
            for (int a = 0; a < 4; ++a)
#pragma unroll
                for (int b = 0; b < 4; ++b) {
                    const float d0 = av[a].x - bv[b].x;
                    const float d1 = av[a].y - bv[b].y;
                    const float d2 = av[a].z - bv[b].z;
                    const float d3 = av[a].w - bv[b].w;
                    acc[a][b] += d0 * d0 + d1 * d1 + d2 * d2 + d3 * d3;
                }
        }

        float* P = planes + (((size_t)m * NKC + kc) << 16);
#pragma unroll
        for (int a = 0; a < 4; ++a) {
            const int gi = ti * 64 + 4 * li + a;
#pragma unroll
            for (int b = 0; b < 4; ++b) {
                const int gj = tj * 64 + 4 * lj + b;
                P[(size_t)gi * NB + gj] = acc[a][b];
            }
        }
    }

    grid.sync();

    // ---------------- Phase 2: triplet loss, ordered-pair form ----------------
    // term(j,k) symmetric in j<->k: sum over ALL ordered pairs = 2x reference sum.
    // j==k contributes exactly 0; j==i term is exactly relu(M - g_ik) (d_ii == 0
    // exactly since As==Bs rows are bit-identical) -> post-loop correction.
    {
        float* Es = lds;          // reuse LDS
        float* Gs = lds + NB;
        const int i    = bid >> 1;
        const int half = bid & 1;

        float sG = 0.0f, sE = 0.0f;
#pragma unroll
        for (int p = 0; p < NKC; ++p) {
            sG += planes[(((size_t)0 * NKC + p) << 16) + (size_t)i * NB + tid];
            sE += planes[(((size_t)1 * NKC + p) << 16) + (size_t)i * NB + tid];
        }
        Gs[tid] = (sG > 0.0f) ? sqrtf(sG) : 0.0f;
        Es[tid] = (sE > 0.0f) ? sqrtf(sE) : 0.0f;
        __syncthreads();

        const int k = tid;
        const float ek = Es[k];
        const float gk = Gs[k];

        float local = 0.0f;
        const int j0 = half << 7;
#pragma unroll 4
        for (int jj = 0; jj < 128; ++jj) {
            const int j = j0 + jj;
            const float ej = Es[j];    // uniform address -> LDS broadcast
            const float gj = Gs[j];
            const float diff = gj - gk;
            const float a = diff + MARGIN_F;     // e_ij < e_ik
            const float b = MARGIN_F - diff;     // e_ik < e_ij
            const float cc = fabsf(diff);        // tie (incl. j==k -> 0)
            const float sel = (ej < ek) ? a : ((ek < ej) ? b : cc);
            local += fmaxf(sel, 0.0f);
        }
        // remove the j==i term added by the loop (exact: d_ii == 0 by construction)
        if (((i >> 7) == half) && (k != i)) local -= fmaxf(MARGIN_F - gk, 0.0f);
        if (k == i) local = 0.0f;   // k must differ from i

        for (int off = 32; off > 0; off >>= 1) local += __shfl_down(local, off, 64);
        const int wid = tid >> 6;
        const int lane = tid & 63;
        if (lane == 0) wred[wid] = local;
        __syncthreads();
        if (tid == 0) partials[bid] = wred[0] + wred[1] + wred[2] + wred[3];
    }

    grid.sync();

    // ---------------- Phase 3: final reduction (block 0, fixed order) ----------------
    if (bid == 0) {
        double v = (double)partials[tid] + (double)partials[tid + 256];
        for (int off = 32; off > 0; off >>= 1) v += __shfl_down(v, off, 64);
        __shared__ double ds4[4];
        const int wid = tid >> 6;
        const int lane = tid & 63;
        if (lane == 0) ds4[wid] = v;
        __syncthreads();
        if (tid == 0) {
            const double total = ds4[0] + ds4[1] + ds4[2] + ds4[3];
            // x0.5 ordered->unordered pairs, / num_triplets (256*255*254/2)
            out[0] = (float)(total * 0.5 / 8290560.0);
        }
    }
}

extern "C" void kernel_launch(void* const* d_in, const int* in_sizes, int n_in,
                              void* d_out, int out_size, void* d_ws, size_t ws_size,
                              hipStream_t stream) {
    const float* img = (const float*)d_in[0];  // img_tokens (256,768)
    const float* ehr = (const float*)d_in[1];  // ehr_tokens (256,768)
    float* out = (float*)d_out;
    float* ws = (float*)d_ws;

    void* args[] = {(void*)&img, (void*)&ehr, (void*)&ws, (void*)&out};
    hipLaunchCooperativeKernel((void*)fused_kernel, dim3(NBLK), dim3(256), args, 0, stream);
}

// Round 5
// 29.066 us; speedup vs baseline: 5.3884x; 5.3884x over previous
//
#include <hip/hip_runtime.h>
#include <math.h>

#define NB 256
#define ND 768
#define MARGIN_F 0.2f
#define NKC 16            // k-chunks per matrix
#define KCF 48            // floats per k-chunk (12 float4)
#define PITCH 64          // LDS row pitch in floats (padded from 48)

// ---------------- k1: d^2 partial planes [2][16][256][256] ----------------
// 512 blocks = 2 matrices x 16 (64x64) tiles x 16 k-chunks; 4x4 register tiling.
// Also resets the k2 arrival counter (safe: k2 starts only after k1 completes).
__global__ __launch_bounds__(256)
void dist_kernel(const float* __restrict__ Ximg,
                 const float* __restrict__ Xehr,
                 float* __restrict__ planes,
                 unsigned int* __restrict__ cnt) {
    __shared__ float As[64 * PITCH];
    __shared__ float Bs[64 * PITCH];

    const int tid = threadIdx.x;
    const int bid = blockIdx.x;
    if (bid == 0 && tid == 0) cnt[0] = 0u;

    const int m    = bid >> 8;        // 0 = img, 1 = ehr
    const int r    = bid & 255;
    const int tile = r >> 4;          // 4x4 grid of 64x64 tiles
    const int kc   = r & 15;
    const int ti   = tile >> 2;
    const int tj   = tile & 3;
    const float* __restrict__ X = m ? Xehr : Ximg;
    const int base_col = kc * KCF;

    // stage 64 rows x 12 float4 per side (768 f4 = 3 x 256), XOR-swizzled
#pragma unroll
    for (int p = 0; p < 3; ++p) {
        const int idx = tid + (p << 8);          // 0..767
        const int row = idx / 12;                // 0..63
        const int c4  = idx - row * 12;          // 0..11
        const int sw  = (row >> 2) & 7;
        const float4 va = *(const float4*)(&X[(size_t)(ti * 64 + row) * ND + base_col + c4 * 4]);
        *(float4*)(&As[row * PITCH + ((c4 ^ sw) << 2)]) = va;
        const float4 vb = *(const float4*)(&X[(size_t)(tj * 64 + row) * ND + base_col + c4 * 4]);
        *(float4*)(&Bs[row * PITCH + ((c4 ^ sw) << 2)]) = vb;
    }
    __syncthreads();

    const int li = tid >> 4;          // rows 4li..4li+3
    const int lj = tid & 15;          // cols 4lj..4lj+3
    const int swa = li & 7;
    const int swb = lj & 7;

    float acc[4][4];
#pragma unroll
    for (int a = 0; a < 4; ++a)
#pragma unroll
        for (int b = 0; b < 4; ++b) acc[a][b] = 0.0f;

#pragma unroll 4
    for (int q = 0; q < 12; ++q) {
        float4 av[4], bv[4];
#pragma unroll
        for (int a = 0; a < 4; ++a)
            av[a] = *(const float4*)(&As[(4 * li + a) * PITCH + ((q ^ swa) << 2)]);
#pragma unroll
        for (int b = 0; b < 4; ++b)
            bv[b] = *(const float4*)(&Bs[(4 * lj + b) * PITCH + ((q ^ swb) << 2)]);
#pragma unroll
        for (int a = 0; a < 4; ++a)
#pragma unroll
            for (int b = 0; b < 4; ++b) {
                const float d0 = av[a].x - bv[b].x;
                const float d1 = av[a].y - bv[b].y;
                const float d2 = av[a].z - bv[b].z;
                const float d3 = av[a].w - bv[b].w;
                acc[a][b] += d0 * d0 + d1 * d1 + d2 * d2 + d3 * d3;
            }
    }

    float* P = planes + (((size_t)m * NKC + kc) << 16);
#pragma unroll
    for (int a = 0; a < 4; ++a) {
        const int gi = ti * 64 + 4 * li + a;
        float4 v;
        v.x = acc[a][0]; v.y = acc[a][1]; v.z = acc[a][2]; v.w = acc[a][3];
        *(float4*)(&P[(size_t)gi * NB + tj * 64 + 4 * lj]) = v;   // coalesced f4 store
    }
}

// ---------------- k2: triplet loss + last-block final reduction ----------------
// 256 blocks (one per i) x 512 threads (two j-halves). Ordered-pair form:
// term(j,k) symmetric -> sum over all ordered pairs = 2x reference; j==k term
// is exactly 0; j==i term is exactly relu(M - g_ik) (d_ii == 0 bit-exactly),
// removed post-loop. Last-arriving block reduces partials in fixed order.
__global__ __launch_bounds__(512)
void triplet_kernel(const float* __restrict__ planes,
                    float* __restrict__ partials,
                    unsigned int* __restrict__ cnt,
                    float* __restrict__ out) {
    __shared__ float Es[NB], Gs[NB];
    __shared__ float pg[2][NB], pe[2][NB];
    __shared__ float wred[8];
    __shared__ int flag;
    __shared__ double dred[8];

    const int tid = threadIdx.x;
    const int i   = blockIdx.x;
    const int k   = tid & 255;
    const int h   = tid >> 8;           // j-half / plane-half

    // rebuild distance row i: each (h,k) sums 8 planes per matrix
    float sg = 0.0f, se = 0.0f;
#pragma unroll
    for (int p = 0; p < 8; ++p) {
        const int pp = h * 8 + p;
        sg += planes[(((size_t)0 * NKC + pp) << 16) + (size_t)i * NB + k];
        se += planes[(((size_t)1 * NKC + pp) << 16) + (size_t)i * NB + k];
    }
    pg[h][k] = sg; pe[h][k] = se;
    __syncthreads();
    if (h == 0) {
        const float g2 = pg[0][k] + pg[1][k];
        const float e2 = pe[0][k] + pe[1][k];
        Gs[k] = (g2 > 0.0f) ? sqrtf(g2) : 0.0f;
        Es[k] = (e2 > 0.0f) ? sqrtf(e2) : 0.0f;
    }
    __syncthreads();

    const float ek = Es[k];
    const float gk = Gs[k];

    float local = 0.0f;
    const int j0 = h << 7;
#pragma unroll 4
    for (int jj = 0; jj < 128; ++jj) {
        const int j = j0 + jj;
        const float ej = Es[j];        // uniform address -> LDS broadcast
        const float gj = Gs[j];
        const float diff = gj - gk;
        const float a = diff + MARGIN_F;     // e_ij < e_ik
        const float b = MARGIN_F - diff;     // e_ik < e_ij
        const float cc = fabsf(diff);        // tie (incl. j==k -> 0)
        const float sel = (ej < ek) ? a : ((ek < ej) ? b : cc);
        local += fmaxf(sel, 0.0f);
    }
    if (((i >> 7) == h) && (k != i)) local -= fmaxf(MARGIN_F - gk, 0.0f);
    if (k == i) local = 0.0f;

    // 8-wave block reduce
    for (int off = 32; off > 0; off >>= 1) local += __shfl_down(local, off, 64);
    const int wid = tid >> 6;
    const int lane = tid & 63;
    if (lane == 0) wred[wid] = local;
    __syncthreads();

    if (tid == 0) {
        float s = 0.0f;
#pragma unroll
        for (int w = 0; w < 8; ++w) s += wred[w];
        __hip_atomic_store(&partials[i], s, __ATOMIC_RELEASE, __HIP_MEMORY_SCOPE_AGENT);
        const unsigned prev = __hip_atomic_fetch_add(cnt, 1u, __ATOMIC_ACQ_REL,
                                                     __HIP_MEMORY_SCOPE_AGENT);
        flag = (prev == NB - 1) ? 1 : 0;
    }
    __syncthreads();

    if (flag) {  // uniform across block
        double v = 0.0;
        if (tid < NB)
            v = (double)__hip_atomic_load(&partials[tid], __ATOMIC_ACQUIRE,
                                          __HIP_MEMORY_SCOPE_AGENT);
        for (int off = 32; off > 0; off >>= 1) v += __shfl_down(v, off, 64);
        if (lane == 0) dred[wid] = v;
        __syncthreads();
        if (tid == 0) {
            double t = 0.0;
#pragma unroll
            for (int w = 0; w < 8; ++w) t += dred[w];
            // x0.5 ordered->unordered, / num_triplets (256*255*254/2)
            out[0] = (float)(t * 0.5 / 8290560.0);
            cnt[0] = 0u;   // leave clean for next replay (k1 also resets)
        }
    }
}

extern "C" void kernel_launch(void* const* d_in, const int* in_sizes, int n_in,
                              void* d_out, int out_size, void* d_ws, size_t ws_size,
                              hipStream_t stream) {
    const float* img = (const float*)d_in[0];  // img_tokens (256,768)
    const float* ehr = (const float*)d_in[1];  // ehr_tokens (256,768)
    float* out = (float*)d_out;

    float* planes   = (float*)d_ws;                       // 2*16*256*256 f32 = 8 MB
    float* partials = planes + 2 * NKC * NB * NB;         // 256 f32
    unsigned int* cnt = (unsigned int*)(partials + NB);   // 1 u32

    dist_kernel<<<dim3(512), 256, 0, stream>>>(img, ehr, planes, cnt);
    triplet_kernel<<<dim3(NB), 512, 0, stream>>>(planes, partials, cnt, out);
}

// Round 6
// 23.777 us; speedup vs baseline: 6.5869x; 1.2224x over previous
//
#include <hip/hip_runtime.h>
#include <math.h>

#define NB 256
#define ND 768
#define MARGIN_F 0.2f
#define NKC 16            // k-chunks per matrix
#define KCF 48            // floats per k-chunk (12 float4)
#define PITCH 64          // LDS row pitch in floats (padded from 48)

// ---------------- k1: d^2 partial planes [2][16][256][256] ----------------
// 512 blocks = 2 matrices x 16 (64x64) tiles x 16 k-chunks; 4x4 register tiling.
__global__ __launch_bounds__(256)
void dist_kernel(const float* __restrict__ Ximg,
                 const float* __restrict__ Xehr,
                 float* __restrict__ planes) {
    __shared__ float As[64 * PITCH];
    __shared__ float Bs[64 * PITCH];

    const int tid = threadIdx.x;
    const int bid = blockIdx.x;

    const int m    = bid >> 8;        // 0 = img, 1 = ehr
    const int r    = bid & 255;
    const int tile = r >> 4;          // 4x4 grid of 64x64 tiles
    const int kc   = r & 15;
    const int ti   = tile >> 2;
    const int tj   = tile & 3;
    const float* __restrict__ X = m ? Xehr : Ximg;
    const int base_col = kc * KCF;

    // stage 64 rows x 12 float4 per side (768 f4 = 3 x 256), XOR-swizzled
#pragma unroll
    for (int p = 0; p < 3; ++p) {
        const int idx = tid + (p << 8);          // 0..767
        const int row = idx / 12;                // 0..63
        const int c4  = idx - row * 12;          // 0..11
        const int sw  = (row >> 2) & 7;
        const float4 va = *(const float4*)(&X[(size_t)(ti * 64 + row) * ND + base_col + c4 * 4]);
        *(float4*)(&As[row * PITCH + ((c4 ^ sw) << 2)]) = va;
        const float4 vb = *(const float4*)(&X[(size_t)(tj * 64 + row) * ND + base_col + c4 * 4]);
        *(float4*)(&Bs[row * PITCH + ((c4 ^ sw) << 2)]) = vb;
    }
    __syncthreads();

    const int li = tid >> 4;          // rows 4li..4li+3
    const int lj = tid & 15;          // cols 4lj..4lj+3
    const int swa = li & 7;
    const int swb = lj & 7;

    float acc[4][4];
#pragma unroll
    for (int a = 0; a < 4; ++a)
#pragma unroll
        for (int b = 0; b < 4; ++b) acc[a][b] = 0.0f;

#pragma unroll 4
    for (int q = 0; q < 12; ++q) {
        float4 av[4], bv[4];
#pragma unroll
        for (int a = 0; a < 4; ++a)
            av[a] = *(const float4*)(&As[(4 * li + a) * PITCH + ((q ^ swa) << 2)]);
#pragma unroll
        for (int b = 0; b < 4; ++b)
            bv[b] = *(const float4*)(&Bs[(4 * lj + b) * PITCH + ((q ^ swb) << 2)]);
#pragma unroll
        for (int a = 0; a < 4; ++a)
#pragma unroll
            for (int b = 0; b < 4; ++b) {
                const float d0 = av[a].x - bv[b].x;
                const float d1 = av[a].y - bv[b].y;
                const float d2 = av[a].z - bv[b].z;
                const float d3 = av[a].w - bv[b].w;
                acc[a][b] += d0 * d0 + d1 * d1 + d2 * d2 + d3 * d3;
            }
    }

    float* P = planes + (((size_t)m * NKC + kc) << 16);
#pragma unroll
    for (int a = 0; a < 4; ++a) {
        const int gi = ti * 64 + 4 * li + a;
        float4 v;
        v.x = acc[a][0]; v.y = acc[a][1]; v.z = acc[a][2]; v.w = acc[a][3];
        *(float4*)(&P[(size_t)gi * NB + tj * 64 + 4 * lj]) = v;   // coalesced f4 store
    }
}

// ---------------- k2: triplet loss per row i ----------------
// 256 blocks (one per i) x 512 threads (two j-halves). Ordered-pair form:
// term(j,k) symmetric -> sum over all ordered pairs = 2x reference; j==k term
// is exactly 0; j==i term is exactly relu(M - g_ik) (d_ii == 0 bit-exactly),
// removed post-loop. Plain store of the per-row partial; no cross-block sync.
__global__ __launch_bounds__(512)
void triplet_kernel(const float* __restrict__ planes,
                    float* __restrict__ partials) {
    __shared__ float Es[NB], Gs[NB];
    __shared__ float pg[2][NB], pe[2][NB];
    __shared__ float wred[8];

    const int tid = threadIdx.x;
    const int i   = blockIdx.x;
    const int k   = tid & 255;
    const int h   = tid >> 8;           // j-half / plane-half

    // rebuild distance row i: each (h,k) sums 8 planes per matrix
    float sg = 0.0f, se = 0.0f;
#pragma unroll
    for (int p = 0; p < 8; ++p) {
        const int pp = h * 8 + p;
        sg += planes[(((size_t)0 * NKC + pp) << 16) + (size_t)i * NB + k];
        se += planes[(((size_t)1 * NKC + pp) << 16) + (size_t)i * NB + k];
    }
    pg[h][k] = sg; pe[h][k] = se;
    __syncthreads();
    if (h == 0) {
        const float g2 = pg[0][k] + pg[1][k];
        const float e2 = pe[0][k] + pe[1][k];
        Gs[k] = (g2 > 0.0f) ? sqrtf(g2) : 0.0f;
        Es[k] = (e2 > 0.0f) ? sqrtf(e2) : 0.0f;
    }
    __syncthreads();

    const float ek = Es[k];
    const float gk = Gs[k];

    float local = 0.0f;
    const int j0 = h << 7;
#pragma unroll 4
    for (int jj = 0; jj < 128; ++jj) {
        const int j = j0 + jj;
        const float ej = Es[j];        // uniform address -> LDS broadcast
        const float gj = Gs[j];
        const float diff = gj - gk;
        const float a = diff + MARGIN_F;     // e_ij < e_ik
        const float b = MARGIN_F - diff;     // e_ik < e_ij
        const float cc = fabsf(diff);        // tie (incl. j==k -> 0)
        const float sel = (ej < ek) ? a : ((ek < ej) ? b : cc);
        local += fmaxf(sel, 0.0f);
    }
    if (((i >> 7) == h) && (k != i)) local -= fmaxf(MARGIN_F - gk, 0.0f);
    if (k == i) local = 0.0f;

    // 8-wave block reduce
    for (int off = 32; off > 0; off >>= 1) local += __shfl_down(local, off, 64);
    const int wid = tid >> 6;
    const int lane = tid & 63;
    if (lane == 0) wred[wid] = local;
    __syncthreads();

    if (tid == 0) {
        float s = 0.0f;
#pragma unroll
        for (int w = 0; w < 8; ++w) s += wred[w];
        partials[i] = s;
    }
}

// ---------------- k3: final reduction (double, fixed order) ----------------
__global__ __launch_bounds__(256)
void reduce_kernel(const float* __restrict__ partials,
                   float* __restrict__ out) {
    const int tid = threadIdx.x;
    double v = (double)partials[tid];
    for (int off = 32; off > 0; off >>= 1) v += __shfl_down(v, off, 64);
    __shared__ double ds4[4];
    const int wid = tid >> 6;
    const int lane = tid & 63;
    if (lane == 0) ds4[wid] = v;
    __syncthreads();
    if (tid == 0) {
        const double total = ds4[0] + ds4[1] + ds4[2] + ds4[3];
        // x0.5 ordered->unordered pairs, / num_triplets (256*255*254/2)
        out[0] = (float)(total * 0.5 / 8290560.0);
    }
}

extern "C" void kernel_launch(void* const* d_in, const int* in_sizes, int n_in,
                              void* d_out, int out_size, void* d_ws, size_t ws_size,
                              hipStream_t stream) {
    const float* img = (const float*)d_in[0];  // img_tokens (256,768)
    const float* ehr = (const float*)d_in[1];  // ehr_tokens (256,768)
    float* out = (float*)d_out;

    float* planes   = (float*)d_ws;                       // 2*16*256*256 f32 = 8 MB
    float* partials = planes + 2 * NKC * NB * NB;         // 256 f32

    dist_kernel<<<dim3(512), 256, 0, stream>>>(img, ehr, planes);
    triplet_kernel<<<dim3(NB), 512, 0, stream>>>(planes, partials);
    reduce_kernel<<<dim3(1), 256, 0, stream>>>(partials, out);
}